// Round 1
// baseline (2293.943 us; speedup 1.0000x reference)
//
#include <hip/hip_runtime.h>
#include <math.h>

#define HD 32      // hidden dim
#define FIN 64     // input features
#define NL 3       // num BernConv layers
#define NC 2       // num classes

// ---------------- degree ----------------
__global__ __launch_bounds__(256) void deg_kernel(const int* __restrict__ dst,
                                                  float* __restrict__ deg, int E) {
    int t = blockIdx.x * 256 + threadIdx.x;
    if (t < E) atomicAdd(&deg[dst[t]], 1.0f);
}

__global__ __launch_bounds__(256) void dinv_kernel(float* __restrict__ deg, int N) {
    int t = blockIdx.x * 256 + threadIdx.x;
    if (t < N) {
        float d = deg[t];
        deg[t] = rsqrtf(fmaxf(d, 1.0f));   // clip(deg,1)^-0.5
    }
}

// ---------------- MLP in: h = relu(feat@W1+b1)@W2+b2 ----------------
__global__ __launch_bounds__(256) void mlp_kernel(const float* __restrict__ feat,
                                                  const float* __restrict__ W1,
                                                  const float* __restrict__ b1,
                                                  const float* __restrict__ W2,
                                                  const float* __restrict__ b2,
                                                  float* __restrict__ hout, int N) {
    __shared__ float sW1[FIN * HD];
    __shared__ float sW2[HD * HD];
    __shared__ float sb1[HD], sb2[HD];
    for (int i = threadIdx.x; i < FIN * HD; i += 256) sW1[i] = W1[i];
    for (int i = threadIdx.x; i < HD * HD; i += 256) sW2[i] = W2[i];
    if (threadIdx.x < HD) { sb1[threadIdx.x] = b1[threadIdx.x]; sb2[threadIdx.x] = b2[threadIdx.x]; }
    __syncthreads();
    int n = blockIdx.x * 256 + threadIdx.x;
    if (n >= N) return;

    float h1[HD];
#pragma unroll
    for (int j = 0; j < HD; ++j) h1[j] = sb1[j];
    const float4* fp = (const float4*)feat;
    for (int k4 = 0; k4 < FIN / 4; ++k4) {
        float4 v = fp[(size_t)n * (FIN / 4) + k4];
        const float* w = &sW1[k4 * 4 * HD];
#pragma unroll
        for (int j = 0; j < HD; ++j)
            h1[j] = fmaf(v.w, w[3 * HD + j],
                    fmaf(v.z, w[2 * HD + j],
                    fmaf(v.y, w[1 * HD + j],
                    fmaf(v.x, w[0 * HD + j], h1[j]))));
    }
    float h2[HD];
#pragma unroll
    for (int j = 0; j < HD; ++j) h2[j] = sb2[j];
#pragma unroll
    for (int k = 0; k < HD; ++k) {
        float a = fmaxf(h1[k], 0.0f);
#pragma unroll
        for (int j = 0; j < HD; ++j) h2[j] = fmaf(a, sW2[k * HD + j], h2[j]);
    }
    float4* op = (float4*)hout;
#pragma unroll
    for (int q = 0; q < HD / 4; ++q) {
        float4 v = {h2[4 * q], h2[4 * q + 1], h2[4 * q + 2], h2[4 * q + 3]};
        op[(size_t)n * (HD / 4) + q] = v;
    }
}

// ---------------- scatter SpMM: out[dst] += x[src]*dinv[src] ----------------
// thread per (edge, 4-feature group); 8 threads per edge
__global__ __launch_bounds__(256) void scatter_kernel(const float* __restrict__ x,
                                                      const float* __restrict__ dinv,
                                                      const int* __restrict__ src,
                                                      const int* __restrict__ dst,
                                                      float* __restrict__ out, int E) {
    int t = blockIdx.x * 256 + threadIdx.x;
    int e = t >> 3;
    if (e >= E) return;
    int q = t & 7;
    int s = src[e], d = dst[e];
    float sc = dinv[s];
    float4 v = ((const float4*)x)[(size_t)s * (HD / 4) + q];
    float* o = out + (size_t)d * HD + q * 4;
    atomicAdd(o + 0, v.x * sc);
    atomicAdd(o + 1, v.y * sc);
    atomicAdd(o + 2, v.z * sc);
    atomicAdd(o + 3, v.w * sc);
}

// ---------------- elementwise: f1 = h + dinv*s0 ; l1 = h - dinv*s0 ----------------
__global__ __launch_bounds__(256) void ew_kernel(const float* __restrict__ h,
                                                 const float* __restrict__ s0,
                                                 const float* __restrict__ dinv,
                                                 float* __restrict__ f1,
                                                 float* __restrict__ l1, int N) {
    int t = blockIdx.x * 256 + threadIdx.x;
    if (t >= N * (HD / 4)) return;
    float di = dinv[t / (HD / 4)];
    float4 hv = ((const float4*)h)[t];
    float4 sv = ((const float4*)s0)[t];
    float4 a = {di * sv.x, di * sv.y, di * sv.z, di * sv.w};
    float4 fo = {hv.x + a.x, hv.y + a.y, hv.z + a.z, hv.w + a.w};
    float4 lo = {hv.x - a.x, hv.y - a.y, hv.z - a.z, hv.w - a.w};
    ((float4*)f1)[t] = fo;
    ((float4*)l1)[t] = lo;
}

// ---------------- fused epilogue ----------------
// f2 = f1 + dinv*s1; g1 = f1 - dinv*s1; g2 = l1 - dinv*s2
// h_i = a_i f2 + b_i g1 + c_i g2 ; attention over 3 filters; out = res@Wc+bc
__global__ __launch_bounds__(256) void final_kernel(const float* __restrict__ h,
                                                    const float* __restrict__ f1,
                                                    const float* __restrict__ l1,
                                                    const float* __restrict__ s1,
                                                    const float* __restrict__ s2,
                                                    const float* __restrict__ dinv,
                                                    const float* __restrict__ W2,
                                                    const float* __restrict__ b2,
                                                    const float* __restrict__ Wc,
                                                    const float* __restrict__ bc,
                                                    const float* __restrict__ wbern,
                                                    float* __restrict__ out, int N) {
    __shared__ float sW2[HD * HD];
    __shared__ float sb2[HD];
    __shared__ float sWc[HD * NC];
    __shared__ float sbc[NC];
    __shared__ float swb[NL * 3];
    for (int i = threadIdx.x; i < HD * HD; i += 256) sW2[i] = W2[i];
    if (threadIdx.x < HD) sb2[threadIdx.x] = b2[threadIdx.x];
    if (threadIdx.x < HD * NC) sWc[threadIdx.x] = Wc[threadIdx.x];
    if (threadIdx.x < NC) sbc[threadIdx.x] = bc[threadIdx.x];
    if (threadIdx.x < NL * 3) swb[threadIdx.x] = wbern[threadIdx.x];
    __syncthreads();
    int n = blockIdx.x * 256 + threadIdx.x;
    if (n >= N) return;
    float di = dinv[n];

    // x_proj = tanh(h@W2+b2)
    float hv[HD];
#pragma unroll
    for (int q = 0; q < HD / 4; ++q) {
        float4 v = ((const float4*)h)[(size_t)n * (HD / 4) + q];
        hv[4 * q] = v.x; hv[4 * q + 1] = v.y; hv[4 * q + 2] = v.z; hv[4 * q + 3] = v.w;
    }
    float xp[HD];
#pragma unroll
    for (int j = 0; j < HD; ++j) {
        float p = sb2[j];
#pragma unroll
        for (int k = 0; k < HD; ++k) p = fmaf(hv[k], sW2[k * HD + j], p);
        xp[j] = tanhf(p);
    }

    // basis vectors
    float f2[HD], g1[HD], g2[HD];
#pragma unroll
    for (int q = 0; q < HD / 4; ++q) {
        float4 fv = ((const float4*)f1)[(size_t)n * (HD / 4) + q];
        float4 av = ((const float4*)s1)[(size_t)n * (HD / 4) + q];
        float4 lv = ((const float4*)l1)[(size_t)n * (HD / 4) + q];
        float4 bv = ((const float4*)s2)[(size_t)n * (HD / 4) + q];
        f2[4 * q + 0] = fv.x + di * av.x; g1[4 * q + 0] = fv.x - di * av.x; g2[4 * q + 0] = lv.x - di * bv.x;
        f2[4 * q + 1] = fv.y + di * av.y; g1[4 * q + 1] = fv.y - di * av.y; g2[4 * q + 1] = lv.y - di * bv.y;
        f2[4 * q + 2] = fv.z + di * av.z; g1[4 * q + 2] = fv.z - di * av.z; g2[4 * q + 2] = lv.z - di * bv.z;
        f2[4 * q + 3] = fv.w + di * av.w; g1[4 * q + 3] = fv.w - di * av.w; g2[4 * q + 3] = lv.w - di * bv.w;
    }

    // per-layer logits
    float logits[NL];
#pragma unroll
    for (int i = 0; i < NL; ++i) {
        float wa = 0.25f * fmaxf(swb[i * 3 + 0], 0.0f);
        float wb = 0.50f * fmaxf(swb[i * 3 + 1], 0.0f);
        float wc = 0.25f * fmaxf(swb[i * 3 + 2], 0.0f);
        float hi[HD];
#pragma unroll
        for (int j = 0; j < HD; ++j)
            hi[j] = wa * f2[j] + wb * g1[j] + wc * g2[j];
        float lg = 0.0f;
#pragma unroll
        for (int j = 0; j < HD; ++j) {
            float p = sb2[j];
#pragma unroll
            for (int k = 0; k < HD; ++k) p = fmaf(hi[k], sW2[k * HD + j], p);
            lg = fmaf(tanhf(p), xp[j], lg);
        }
        logits[i] = lg;
    }

    // softmax over 3
    float m = fmaxf(logits[0], fmaxf(logits[1], logits[2]));
    float e0 = expf(logits[0] - m), e1 = expf(logits[1] - m), e2 = expf(logits[2] - m);
    float inv = 1.0f / (e0 + e1 + e2);
    float sc0 = e0 * inv, sc1 = e1 * inv, sc2 = e2 * inv;

    // res = sum_i score_i h_i  is linear in (f2,g1,g2): blend coefficients
    float A = 0.0f, B = 0.0f, Cc = 0.0f;
    float scs[NL] = {sc0, sc1, sc2};
#pragma unroll
    for (int i = 0; i < NL; ++i) {
        A  += scs[i] * 0.25f * fmaxf(swb[i * 3 + 0], 0.0f);
        B  += scs[i] * 0.50f * fmaxf(swb[i * 3 + 1], 0.0f);
        Cc += scs[i] * 0.25f * fmaxf(swb[i * 3 + 2], 0.0f);
    }
    float o0 = sbc[0], o1 = sbc[1];
#pragma unroll
    for (int j = 0; j < HD; ++j) {
        float rj = A * f2[j] + B * g1[j] + Cc * g2[j];
        o0 = fmaf(rj, sWc[j * NC + 0], o0);
        o1 = fmaf(rj, sWc[j * NC + 1], o1);
    }
    out[(size_t)n * NC + 0] = o0;
    out[(size_t)n * NC + 1] = o1;
}

extern "C" void kernel_launch(void* const* d_in, const int* in_sizes, int n_in,
                              void* d_out, int out_size, void* d_ws, size_t ws_size,
                              hipStream_t stream) {
    const float* feature = (const float*)d_in[0];
    const float* W1 = (const float*)d_in[1];
    const float* b1 = (const float*)d_in[2];
    const float* W2 = (const float*)d_in[3];
    const float* b2 = (const float*)d_in[4];
    const float* Wc = (const float*)d_in[5];
    const float* bc = (const float*)d_in[6];
    const float* wbern = (const float*)d_in[7];
    const int* src = (const int*)d_in[8];
    const int* dst = (const int*)d_in[9];

    const int N = in_sizes[0] / FIN;   // 100000
    const int E = in_sizes[8];         // 1600000

    // workspace layout (floats)
    float* ws = (float*)d_ws;
    size_t Np = ((size_t)N + 127) & ~(size_t)127;
    size_t N32 = (size_t)N * HD;
    float* deg = ws;                 // N   (becomes dinv in place)
    float* h   = ws + Np;            // 32N
    float* f1  = h + N32;            // 32N
    float* l1  = f1 + N32;           // 32N
    float* s0  = l1 + N32;           // 32N (reused as s1)
    float* s2  = s0 + N32;           // 32N
    // total = Np + 160N floats ~ 64.5 MB

    hipMemsetAsync(deg, 0, Np * sizeof(float), stream);
    hipMemsetAsync(s0, 0, 2 * N32 * sizeof(float), stream);  // s0 and s2 (contiguous)

    int bE = (E + 255) / 256;
    int bN = (N + 255) / 256;
    int bS = ((E * 8) + 255) / 256;
    int bW = ((N * (HD / 4)) + 255) / 256;

    deg_kernel<<<bE, 256, 0, stream>>>(dst, deg, E);
    dinv_kernel<<<bN, 256, 0, stream>>>(deg, N);
    mlp_kernel<<<bN, 256, 0, stream>>>(feature, W1, b1, W2, b2, h, N);

    // s0 = scatter(h * dinv)
    scatter_kernel<<<bS, 256, 0, stream>>>(h, deg, src, dst, s0, E);
    // f1 = h + dinv*s0 ; l1 = h - dinv*s0
    ew_kernel<<<bW, 256, 0, stream>>>(h, s0, deg, f1, l1, N);

    // reuse s0 as s1
    hipMemsetAsync(s0, 0, N32 * sizeof(float), stream);
    scatter_kernel<<<bS, 256, 0, stream>>>(f1, deg, src, dst, s0, E);
    scatter_kernel<<<bS, 256, 0, stream>>>(l1, deg, src, dst, s2, E);

    final_kernel<<<bN, 256, 0, stream>>>(h, f1, l1, s0, s2, deg, W2, b2, Wc, bc,
                                         wbern, (float*)d_out, N);
}

// Round 2
// 555.516 us; speedup vs baseline: 4.1294x; 4.1294x over previous
//
#include <hip/hip_runtime.h>
#include <math.h>

#define HD 32      // hidden dim
#define FIN 64     // input features
#define NL 3       // num BernConv layers
#define NC 2       // num classes

// ---------------- degree count (int) ----------------
__global__ __launch_bounds__(256) void deg_kernel(const int* __restrict__ dst,
                                                  int* __restrict__ deg, int E) {
    int t = blockIdx.x * 256 + threadIdx.x;
    if (t < E) atomicAdd(&deg[dst[t]], 1);
}

// ---------------- block-level exclusive scan ----------------
__global__ __launch_bounds__(256) void scan_block_kernel(const int* __restrict__ deg,
                                                         int* __restrict__ row_start,
                                                         int* __restrict__ blockSums, int N) {
    __shared__ int tmp[256];
    int t = blockIdx.x * 256 + threadIdx.x;
    int v = (t < N) ? deg[t] : 0;
    tmp[threadIdx.x] = v;
    __syncthreads();
    for (int off = 1; off < 256; off <<= 1) {
        int add = (threadIdx.x >= off) ? tmp[threadIdx.x - off] : 0;
        __syncthreads();
        tmp[threadIdx.x] += add;
        __syncthreads();
    }
    if (t < N) row_start[t] = tmp[threadIdx.x] - v;   // exclusive within block
    if (threadIdx.x == 255) blockSums[blockIdx.x] = tmp[255];
}

// single block scan of block sums (nb <= 512)
__global__ __launch_bounds__(512) void scan_sums_kernel(int* __restrict__ blockSums, int nb) {
    __shared__ int tmp[512];
    int t = threadIdx.x;
    int v = (t < nb) ? blockSums[t] : 0;
    tmp[t] = v;
    __syncthreads();
    for (int off = 1; off < 512; off <<= 1) {
        int add = (t >= off) ? tmp[t - off] : 0;
        __syncthreads();
        tmp[t] += add;
        __syncthreads();
    }
    if (t < nb) blockSums[t] = tmp[t] - v;            // exclusive
}

// row_start += blockOffset; cursor = row_start; dinv = rsqrt(max(deg,1))
__global__ __launch_bounds__(256) void finalize_csr_kernel(int* __restrict__ row_start,
                                                           const int* __restrict__ blockSums,
                                                           int* __restrict__ cursor,
                                                           const int* __restrict__ deg,
                                                           float* __restrict__ dinv, int N) {
    int t = blockIdx.x * 256 + threadIdx.x;
    if (t >= N) return;
    int rs = row_start[t] + blockSums[t >> 8];
    row_start[t] = rs;
    cursor[t] = rs;
    dinv[t] = rsqrtf(fmaxf((float)deg[t], 1.0f));
}

// bucket edges by dst: col[slot] = src
__global__ __launch_bounds__(256) void fill_kernel(const int* __restrict__ src,
                                                   const int* __restrict__ dst,
                                                   int* __restrict__ cursor,
                                                   int* __restrict__ col, int E) {
    int e = blockIdx.x * 256 + threadIdx.x;
    if (e >= E) return;
    int d = dst[e];
    int p = atomicAdd(&cursor[d], 1);
    col[p] = src[e];
}

// ---------------- MLP in: h = relu(feat@W1+b1)@W2+b2 ----------------
__global__ __launch_bounds__(256) void mlp_kernel(const float* __restrict__ feat,
                                                  const float* __restrict__ W1,
                                                  const float* __restrict__ b1,
                                                  const float* __restrict__ W2,
                                                  const float* __restrict__ b2,
                                                  float* __restrict__ hout, int N) {
    __shared__ float sW1[FIN * HD];
    __shared__ float sW2[HD * HD];
    __shared__ float sb1[HD], sb2[HD];
    for (int i = threadIdx.x; i < FIN * HD; i += 256) sW1[i] = W1[i];
    for (int i = threadIdx.x; i < HD * HD; i += 256) sW2[i] = W2[i];
    if (threadIdx.x < HD) { sb1[threadIdx.x] = b1[threadIdx.x]; sb2[threadIdx.x] = b2[threadIdx.x]; }
    __syncthreads();
    int n = blockIdx.x * 256 + threadIdx.x;
    if (n >= N) return;

    float h1[HD];
#pragma unroll
    for (int j = 0; j < HD; ++j) h1[j] = sb1[j];
    const float4* fp = (const float4*)feat;
    for (int k4 = 0; k4 < FIN / 4; ++k4) {
        float4 v = fp[(size_t)n * (FIN / 4) + k4];
        const float* w = &sW1[k4 * 4 * HD];
#pragma unroll
        for (int j = 0; j < HD; ++j)
            h1[j] = fmaf(v.w, w[3 * HD + j],
                    fmaf(v.z, w[2 * HD + j],
                    fmaf(v.y, w[1 * HD + j],
                    fmaf(v.x, w[0 * HD + j], h1[j]))));
    }
    float h2[HD];
#pragma unroll
    for (int j = 0; j < HD; ++j) h2[j] = sb2[j];
#pragma unroll
    for (int k = 0; k < HD; ++k) {
        float a = fmaxf(h1[k], 0.0f);
#pragma unroll
        for (int j = 0; j < HD; ++j) h2[j] = fmaf(a, sW2[k * HD + j], h2[j]);
    }
    float4* op = (float4*)hout;
#pragma unroll
    for (int q = 0; q < HD / 4; ++q) {
        float4 v = {h2[4 * q], h2[4 * q + 1], h2[4 * q + 2], h2[4 * q + 3]};
        op[(size_t)n * (HD / 4) + q] = v;
    }
}

// ---------------- gather SpMM: out[v] = sum_{e in row v} dinv[col]*x[col] ----------------
// 8 threads per node, thread q handles float4 quad q
__global__ __launch_bounds__(256) void gather1_kernel(const float* __restrict__ x,
                                                      const float* __restrict__ dinv,
                                                      const int* __restrict__ row_start,
                                                      const int* __restrict__ deg,
                                                      const int* __restrict__ col,
                                                      float* __restrict__ out, int N) {
    int t = blockIdx.x * 256 + threadIdx.x;
    int n = t >> 3;
    if (n >= N) return;
    int q = t & 7;
    int s = row_start[n];
    int e_end = s + deg[n];
    float4 acc = {0.f, 0.f, 0.f, 0.f};
    const float4* x4 = (const float4*)x;
    for (int e = s; e < e_end; ++e) {
        int c = col[e];
        float sc = dinv[c];
        float4 v = x4[(size_t)c * 8 + q];
        acc.x = fmaf(v.x, sc, acc.x);
        acc.y = fmaf(v.y, sc, acc.y);
        acc.z = fmaf(v.z, sc, acc.z);
        acc.w = fmaf(v.w, sc, acc.w);
    }
    ((float4*)out)[(size_t)n * 8 + q] = acc;
}

// fused double gather: t1 = spmm(f1), t2 = spmm(l1) — one edge walk
__global__ __launch_bounds__(256) void gather2_kernel(const float* __restrict__ f1,
                                                      const float* __restrict__ l1,
                                                      const float* __restrict__ dinv,
                                                      const int* __restrict__ row_start,
                                                      const int* __restrict__ deg,
                                                      const int* __restrict__ col,
                                                      float* __restrict__ t1,
                                                      float* __restrict__ t2, int N) {
    int t = blockIdx.x * 256 + threadIdx.x;
    int n = t >> 3;
    if (n >= N) return;
    int q = t & 7;
    int s = row_start[n];
    int e_end = s + deg[n];
    float4 a1 = {0.f, 0.f, 0.f, 0.f};
    float4 a2 = {0.f, 0.f, 0.f, 0.f};
    const float4* x1 = (const float4*)f1;
    const float4* x2 = (const float4*)l1;
    for (int e = s; e < e_end; ++e) {
        int c = col[e];
        float sc = dinv[c];
        float4 v1 = x1[(size_t)c * 8 + q];
        float4 v2 = x2[(size_t)c * 8 + q];
        a1.x = fmaf(v1.x, sc, a1.x); a1.y = fmaf(v1.y, sc, a1.y);
        a1.z = fmaf(v1.z, sc, a1.z); a1.w = fmaf(v1.w, sc, a1.w);
        a2.x = fmaf(v2.x, sc, a2.x); a2.y = fmaf(v2.y, sc, a2.y);
        a2.z = fmaf(v2.z, sc, a2.z); a2.w = fmaf(v2.w, sc, a2.w);
    }
    ((float4*)t1)[(size_t)n * 8 + q] = a1;
    ((float4*)t2)[(size_t)n * 8 + q] = a2;
}

// ---------------- elementwise: f1 = h + dinv*s0 ; l1 = h - dinv*s0 ----------------
__global__ __launch_bounds__(256) void ew_kernel(const float* __restrict__ h,
                                                 const float* __restrict__ s0,
                                                 const float* __restrict__ dinv,
                                                 float* __restrict__ f1,
                                                 float* __restrict__ l1, int N) {
    int t = blockIdx.x * 256 + threadIdx.x;
    if (t >= N * (HD / 4)) return;
    float di = dinv[t / (HD / 4)];
    float4 hv = ((const float4*)h)[t];
    float4 sv = ((const float4*)s0)[t];
    float4 a = {di * sv.x, di * sv.y, di * sv.z, di * sv.w};
    float4 fo = {hv.x + a.x, hv.y + a.y, hv.z + a.z, hv.w + a.w};
    float4 lo = {hv.x - a.x, hv.y - a.y, hv.z - a.z, hv.w - a.w};
    ((float4*)f1)[t] = fo;
    ((float4*)l1)[t] = lo;
}

// ---------------- fused epilogue ----------------
__global__ __launch_bounds__(256) void final_kernel(const float* __restrict__ h,
                                                    const float* __restrict__ f1,
                                                    const float* __restrict__ l1,
                                                    const float* __restrict__ s1,
                                                    const float* __restrict__ s2,
                                                    const float* __restrict__ dinv,
                                                    const float* __restrict__ W2,
                                                    const float* __restrict__ b2,
                                                    const float* __restrict__ Wc,
                                                    const float* __restrict__ bc,
                                                    const float* __restrict__ wbern,
                                                    float* __restrict__ out, int N) {
    __shared__ float sW2[HD * HD];
    __shared__ float sb2[HD];
    __shared__ float sWc[HD * NC];
    __shared__ float sbc[NC];
    __shared__ float swb[NL * 3];
    for (int i = threadIdx.x; i < HD * HD; i += 256) sW2[i] = W2[i];
    if (threadIdx.x < HD) sb2[threadIdx.x] = b2[threadIdx.x];
    if (threadIdx.x < HD * NC) sWc[threadIdx.x] = Wc[threadIdx.x];
    if (threadIdx.x < NC) sbc[threadIdx.x] = bc[threadIdx.x];
    if (threadIdx.x < NL * 3) swb[threadIdx.x] = wbern[threadIdx.x];
    __syncthreads();
    int n = blockIdx.x * 256 + threadIdx.x;
    if (n >= N) return;
    float di = dinv[n];

    float hv[HD];
#pragma unroll
    for (int q = 0; q < HD / 4; ++q) {
        float4 v = ((const float4*)h)[(size_t)n * (HD / 4) + q];
        hv[4 * q] = v.x; hv[4 * q + 1] = v.y; hv[4 * q + 2] = v.z; hv[4 * q + 3] = v.w;
    }
    float xp[HD];
#pragma unroll
    for (int j = 0; j < HD; ++j) {
        float p = sb2[j];
#pragma unroll
        for (int k = 0; k < HD; ++k) p = fmaf(hv[k], sW2[k * HD + j], p);
        xp[j] = tanhf(p);
    }

    float f2[HD], g1[HD], g2[HD];
#pragma unroll
    for (int q = 0; q < HD / 4; ++q) {
        float4 fv = ((const float4*)f1)[(size_t)n * (HD / 4) + q];
        float4 av = ((const float4*)s1)[(size_t)n * (HD / 4) + q];
        float4 lv = ((const float4*)l1)[(size_t)n * (HD / 4) + q];
        float4 bv = ((const float4*)s2)[(size_t)n * (HD / 4) + q];
        f2[4 * q + 0] = fv.x + di * av.x; g1[4 * q + 0] = fv.x - di * av.x; g2[4 * q + 0] = lv.x - di * bv.x;
        f2[4 * q + 1] = fv.y + di * av.y; g1[4 * q + 1] = fv.y - di * av.y; g2[4 * q + 1] = lv.y - di * bv.y;
        f2[4 * q + 2] = fv.z + di * av.z; g1[4 * q + 2] = fv.z - di * av.z; g2[4 * q + 2] = lv.z - di * bv.z;
        f2[4 * q + 3] = fv.w + di * av.w; g1[4 * q + 3] = fv.w - di * av.w; g2[4 * q + 3] = lv.w - di * bv.w;
    }

    float logits[NL];
#pragma unroll
    for (int i = 0; i < NL; ++i) {
        float wa = 0.25f * fmaxf(swb[i * 3 + 0], 0.0f);
        float wb = 0.50f * fmaxf(swb[i * 3 + 1], 0.0f);
        float wc = 0.25f * fmaxf(swb[i * 3 + 2], 0.0f);
        float hi[HD];
#pragma unroll
        for (int j = 0; j < HD; ++j)
            hi[j] = wa * f2[j] + wb * g1[j] + wc * g2[j];
        float lg = 0.0f;
#pragma unroll
        for (int j = 0; j < HD; ++j) {
            float p = sb2[j];
#pragma unroll
            for (int k = 0; k < HD; ++k) p = fmaf(hi[k], sW2[k * HD + j], p);
            lg = fmaf(tanhf(p), xp[j], lg);
        }
        logits[i] = lg;
    }

    float m = fmaxf(logits[0], fmaxf(logits[1], logits[2]));
    float e0 = expf(logits[0] - m), e1 = expf(logits[1] - m), e2 = expf(logits[2] - m);
    float inv = 1.0f / (e0 + e1 + e2);
    float scs[NL] = {e0 * inv, e1 * inv, e2 * inv};

    float A = 0.0f, B = 0.0f, Cc = 0.0f;
#pragma unroll
    for (int i = 0; i < NL; ++i) {
        A  += scs[i] * 0.25f * fmaxf(swb[i * 3 + 0], 0.0f);
        B  += scs[i] * 0.50f * fmaxf(swb[i * 3 + 1], 0.0f);
        Cc += scs[i] * 0.25f * fmaxf(swb[i * 3 + 2], 0.0f);
    }
    float o0 = sbc[0], o1 = sbc[1];
#pragma unroll
    for (int j = 0; j < HD; ++j) {
        float rj = A * f2[j] + B * g1[j] + Cc * g2[j];
        o0 = fmaf(rj, sWc[j * NC + 0], o0);
        o1 = fmaf(rj, sWc[j * NC + 1], o1);
    }
    out[(size_t)n * NC + 0] = o0;
    out[(size_t)n * NC + 1] = o1;
}

extern "C" void kernel_launch(void* const* d_in, const int* in_sizes, int n_in,
                              void* d_out, int out_size, void* d_ws, size_t ws_size,
                              hipStream_t stream) {
    const float* feature = (const float*)d_in[0];
    const float* W1 = (const float*)d_in[1];
    const float* b1 = (const float*)d_in[2];
    const float* W2 = (const float*)d_in[3];
    const float* b2 = (const float*)d_in[4];
    const float* Wc = (const float*)d_in[5];
    const float* bc = (const float*)d_in[6];
    const float* wbern = (const float*)d_in[7];
    const int* src = (const int*)d_in[8];
    const int* dst = (const int*)d_in[9];

    const int N = in_sizes[0] / FIN;   // 100000
    const int E = in_sizes[8];         // 1600000

    // workspace layout
    char* p = (char*)d_ws;
    size_t Np = ((size_t)N + 255) & ~(size_t)255;
    size_t N32 = (size_t)N * HD;
    int* deg_i     = (int*)p;              p += Np * 4;
    int* row_start = (int*)p;              p += Np * 4;
    int* cursor    = (int*)p;              p += Np * 4;
    int* blockSums = (int*)p;              p += 512 * 4;
    float* dinv    = (float*)p;            p += Np * 4;
    int* col       = (int*)p;              p += ((size_t)E + 255 & ~(size_t)255) * 4;
    float* h  = (float*)p;                 p += N32 * 4;
    float* f1 = (float*)p;                 p += N32 * 4;
    float* l1 = (float*)p;                 p += N32 * 4;
    float* s0 = (float*)p;                 p += N32 * 4;   // reused as t1
    float* t2 = (float*)p;                 p += N32 * 4;

    hipMemsetAsync(deg_i, 0, Np * 4, stream);

    int bE = (E + 255) / 256;
    int bN = (N + 255) / 256;
    int nb = bN;                       // number of scan blocks
    int bG = ((N * 8) + 255) / 256;
    int bW = ((N * (HD / 4)) + 255) / 256;

    deg_kernel<<<bE, 256, 0, stream>>>(dst, deg_i, E);
    scan_block_kernel<<<bN, 256, 0, stream>>>(deg_i, row_start, blockSums, N);
    scan_sums_kernel<<<1, 512, 0, stream>>>(blockSums, nb);
    finalize_csr_kernel<<<bN, 256, 0, stream>>>(row_start, blockSums, cursor, deg_i, dinv, N);
    fill_kernel<<<bE, 256, 0, stream>>>(src, dst, cursor, col, E);

    mlp_kernel<<<bN, 256, 0, stream>>>(feature, W1, b1, W2, b2, h, N);

    // s0 = spmm(h)
    gather1_kernel<<<bG, 256, 0, stream>>>(h, dinv, row_start, deg_i, col, s0, N);
    // f1 = h + dinv*s0 ; l1 = h - dinv*s0
    ew_kernel<<<bW, 256, 0, stream>>>(h, s0, dinv, f1, l1, N);
    // t1 = spmm(f1) (into s0), t2 = spmm(l1) — fused edge walk
    gather2_kernel<<<bG, 256, 0, stream>>>(f1, l1, dinv, row_start, deg_i, col, s0, t2, N);

    final_kernel<<<bN, 256, 0, stream>>>(h, f1, l1, s0, t2, dinv, W2, b2, Wc, bc,
                                         wbern, (float*)d_out, N);
}

// Round 3
// 449.027 us; speedup vs baseline: 5.1087x; 1.2372x over previous
//
#include <hip/hip_runtime.h>
#include <math.h>

#define HD 32      // hidden dim
#define FIN 64     // input features
#define NL 3       // num BernConv layers
#define NC 2       // num classes

// fast tanh: 1 - 2/(exp(2x)+1). exp->v_exp_f32, rcp->v_rcp_f32.
// Correct limits: x->+inf => 1, x->-inf => -1. |err| ~1e-7 rel, threshold is 7e-2.
__device__ __forceinline__ float fast_tanh(float x) {
    float e = __expf(2.0f * x);
    return 1.0f - 2.0f * __builtin_amdgcn_rcpf(e + 1.0f);
}

// ---------------- degree count (int) ----------------
__global__ __launch_bounds__(256) void deg_kernel(const int* __restrict__ dst,
                                                  int* __restrict__ deg, int E) {
    int t = blockIdx.x * 256 + threadIdx.x;
    if (t < E) atomicAdd(&deg[dst[t]], 1);
}

// ---------------- block-level exclusive scan ----------------
__global__ __launch_bounds__(256) void scan_block_kernel(const int* __restrict__ deg,
                                                         int* __restrict__ row_start,
                                                         int* __restrict__ blockSums, int N) {
    __shared__ int tmp[256];
    int t = blockIdx.x * 256 + threadIdx.x;
    int v = (t < N) ? deg[t] : 0;
    tmp[threadIdx.x] = v;
    __syncthreads();
    for (int off = 1; off < 256; off <<= 1) {
        int add = (threadIdx.x >= off) ? tmp[threadIdx.x - off] : 0;
        __syncthreads();
        tmp[threadIdx.x] += add;
        __syncthreads();
    }
    if (t < N) row_start[t] = tmp[threadIdx.x] - v;   // exclusive within block
    if (threadIdx.x == 255) blockSums[blockIdx.x] = tmp[255];
}

// single block scan of block sums (nb <= 512)
__global__ __launch_bounds__(512) void scan_sums_kernel(int* __restrict__ blockSums, int nb) {
    __shared__ int tmp[512];
    int t = threadIdx.x;
    int v = (t < nb) ? blockSums[t] : 0;
    tmp[t] = v;
    __syncthreads();
    for (int off = 1; off < 512; off <<= 1) {
        int add = (t >= off) ? tmp[t - off] : 0;
        __syncthreads();
        tmp[t] += add;
        __syncthreads();
    }
    if (t < nb) blockSums[t] = tmp[t] - v;            // exclusive
}

// row_start += blockOffset; cursor = row_start; dinv = rsqrt(max(deg,1))
__global__ __launch_bounds__(256) void finalize_csr_kernel(int* __restrict__ row_start,
                                                           const int* __restrict__ blockSums,
                                                           int* __restrict__ cursor,
                                                           const int* __restrict__ deg,
                                                           float* __restrict__ dinv, int N) {
    int t = blockIdx.x * 256 + threadIdx.x;
    if (t >= N) return;
    int rs = row_start[t] + blockSums[t >> 8];
    row_start[t] = rs;
    cursor[t] = rs;
    dinv[t] = rsqrtf(fmaxf((float)deg[t], 1.0f));
}

// bucket edges by dst: col[slot] = src
__global__ __launch_bounds__(256) void fill_kernel(const int* __restrict__ src,
                                                   const int* __restrict__ dst,
                                                   int* __restrict__ cursor,
                                                   int* __restrict__ col, int E) {
    int e = blockIdx.x * 256 + threadIdx.x;
    if (e >= E) return;
    int d = dst[e];
    int p = atomicAdd(&cursor[d], 1);
    col[p] = src[e];
}

// ---------------- MLP in: h = relu(feat@W1+b1)@W2+b2 ----------------
// Weights read straight from global: wave-uniform compile-time-offset loads
// become s_load_dwordx16 + FMA-with-SGPR — no LDS, no weight VGPRs.
__global__ __launch_bounds__(256) void mlp_kernel(const float* __restrict__ feat,
                                                  const float* __restrict__ W1,
                                                  const float* __restrict__ b1,
                                                  const float* __restrict__ W2,
                                                  const float* __restrict__ b2,
                                                  float* __restrict__ hout, int N) {
    int n = blockIdx.x * 256 + threadIdx.x;
    if (n >= N) return;

    float h1[HD];
#pragma unroll
    for (int j = 0; j < HD; ++j) h1[j] = b1[j];
    const float4* fp = (const float4*)feat;
#pragma unroll
    for (int k4 = 0; k4 < FIN / 4; ++k4) {
        float4 v = fp[(size_t)n * (FIN / 4) + k4];
        const float* w = &W1[k4 * 4 * HD];
#pragma unroll
        for (int j = 0; j < HD; ++j)
            h1[j] = fmaf(v.w, w[3 * HD + j],
                    fmaf(v.z, w[2 * HD + j],
                    fmaf(v.y, w[1 * HD + j],
                    fmaf(v.x, w[0 * HD + j], h1[j]))));
    }
    float h2[HD];
#pragma unroll
    for (int j = 0; j < HD; ++j) h2[j] = b2[j];
#pragma unroll
    for (int k = 0; k < HD; ++k) {
        float a = fmaxf(h1[k], 0.0f);
#pragma unroll
        for (int j = 0; j < HD; ++j) h2[j] = fmaf(a, W2[k * HD + j], h2[j]);
    }
    float4* op = (float4*)hout;
#pragma unroll
    for (int q = 0; q < HD / 4; ++q) {
        float4 v = {h2[4 * q], h2[4 * q + 1], h2[4 * q + 2], h2[4 * q + 3]};
        op[(size_t)n * (HD / 4) + q] = v;
    }
}

// ---------------- gather SpMM #1 fused with lap combine ----------------
// acc = S(dinv*h)[n] quad; f1 = h + dinv[n]*acc ; l1 = h - dinv[n]*acc
__global__ __launch_bounds__(256) void gather1_kernel(const float* __restrict__ h,
                                                      const float* __restrict__ dinv,
                                                      const int* __restrict__ row_start,
                                                      const int* __restrict__ deg,
                                                      const int* __restrict__ col,
                                                      float* __restrict__ f1,
                                                      float* __restrict__ l1, int N) {
    int t = blockIdx.x * 256 + threadIdx.x;
    int n = t >> 3;
    if (n >= N) return;
    int q = t & 7;
    int s = row_start[n];
    int e_end = s + deg[n];
    float4 acc = {0.f, 0.f, 0.f, 0.f};
    const float4* x4 = (const float4*)h;
    for (int e = s; e < e_end; ++e) {
        int c = col[e];
        float sc = dinv[c];
        float4 v = x4[(size_t)c * 8 + q];
        acc.x = fmaf(v.x, sc, acc.x);
        acc.y = fmaf(v.y, sc, acc.y);
        acc.z = fmaf(v.z, sc, acc.z);
        acc.w = fmaf(v.w, sc, acc.w);
    }
    float di = dinv[n];
    float4 hv = x4[(size_t)n * 8 + q];
    float4 fo = {fmaf(di, acc.x, hv.x), fmaf(di, acc.y, hv.y),
                 fmaf(di, acc.z, hv.z), fmaf(di, acc.w, hv.w)};
    float4 lo = {fmaf(-di, acc.x, hv.x), fmaf(-di, acc.y, hv.y),
                 fmaf(-di, acc.z, hv.z), fmaf(-di, acc.w, hv.w)};
    ((float4*)f1)[(size_t)n * 8 + q] = fo;
    ((float4*)l1)[(size_t)n * 8 + q] = lo;
}

// fused double gather: t1 = S(dinv*f1), t2 = S(dinv*l1) — one edge walk
__global__ __launch_bounds__(256) void gather2_kernel(const float* __restrict__ f1,
                                                      const float* __restrict__ l1,
                                                      const float* __restrict__ dinv,
                                                      const int* __restrict__ row_start,
                                                      const int* __restrict__ deg,
                                                      const int* __restrict__ col,
                                                      float* __restrict__ t1,
                                                      float* __restrict__ t2, int N) {
    int t = blockIdx.x * 256 + threadIdx.x;
    int n = t >> 3;
    if (n >= N) return;
    int q = t & 7;
    int s = row_start[n];
    int e_end = s + deg[n];
    float4 a1 = {0.f, 0.f, 0.f, 0.f};
    float4 a2 = {0.f, 0.f, 0.f, 0.f};
    const float4* x1 = (const float4*)f1;
    const float4* x2 = (const float4*)l1;
    for (int e = s; e < e_end; ++e) {
        int c = col[e];
        float sc = dinv[c];
        float4 v1 = x1[(size_t)c * 8 + q];
        float4 v2 = x2[(size_t)c * 8 + q];
        a1.x = fmaf(v1.x, sc, a1.x); a1.y = fmaf(v1.y, sc, a1.y);
        a1.z = fmaf(v1.z, sc, a1.z); a1.w = fmaf(v1.w, sc, a1.w);
        a2.x = fmaf(v2.x, sc, a2.x); a2.y = fmaf(v2.y, sc, a2.y);
        a2.z = fmaf(v2.z, sc, a2.z); a2.w = fmaf(v2.w, sc, a2.w);
    }
    ((float4*)t1)[(size_t)n * 8 + q] = a1;
    ((float4*)t2)[(size_t)n * 8 + q] = a2;
}

// ---------------- fused epilogue ----------------
// Stream f2/g1/g2 quad-by-quad, accumulating uf=f2@W2, ug=g1@W2, uh=g2@W2
// (and 6 scalars for @Wc). Per-layer pre-tanh = wa*uf + wb*ug + wc*uh + b2.
// fast_tanh replaces libm tanhf (128 calls/node was the round-2 sink).
__global__ __launch_bounds__(256) void final_kernel(const float* __restrict__ h,
                                                    const float* __restrict__ f1,
                                                    const float* __restrict__ l1,
                                                    const float* __restrict__ s1,
                                                    const float* __restrict__ s2,
                                                    const float* __restrict__ dinv,
                                                    const float* __restrict__ W2,
                                                    const float* __restrict__ b2,
                                                    const float* __restrict__ Wc,
                                                    const float* __restrict__ bc,
                                                    const float* __restrict__ wbern,
                                                    float* __restrict__ out, int N) {
    int n = blockIdx.x * 256 + threadIdx.x;
    if (n >= N) return;
    float di = dinv[n];

    // xp = tanh(h@W2 + b2)
    float xp[HD];
#pragma unroll
    for (int j = 0; j < HD; ++j) xp[j] = b2[j];
    const float4* h4 = (const float4*)h;
#pragma unroll
    for (int q = 0; q < 8; ++q) {
        float4 v = h4[(size_t)n * 8 + q];
        const float* w = &W2[q * 4 * HD];
#pragma unroll
        for (int j = 0; j < HD; ++j)
            xp[j] = fmaf(v.w, w[3 * HD + j],
                    fmaf(v.z, w[2 * HD + j],
                    fmaf(v.y, w[1 * HD + j],
                    fmaf(v.x, w[0 * HD + j], xp[j]))));
    }
#pragma unroll
    for (int j = 0; j < HD; ++j) xp[j] = fast_tanh(xp[j]);

    // stream basis quads; accumulate W2 and Wc projections
    float uf[HD], ug[HD], uh[HD];
#pragma unroll
    for (int j = 0; j < HD; ++j) { uf[j] = 0.f; ug[j] = 0.f; uh[j] = 0.f; }
    float vf0 = 0.f, vf1 = 0.f, vg0 = 0.f, vg1 = 0.f, vh0 = 0.f, vh1 = 0.f;
    const float4* f14 = (const float4*)f1;
    const float4* l14 = (const float4*)l1;
    const float4* s14 = (const float4*)s1;
    const float4* s24 = (const float4*)s2;
#pragma unroll
    for (int q = 0; q < 8; ++q) {
        float4 fv = f14[(size_t)n * 8 + q];
        float4 av = s14[(size_t)n * 8 + q];
        float4 lv = l14[(size_t)n * 8 + q];
        float4 bv = s24[(size_t)n * 8 + q];
        float f2k[4] = {fmaf(di, av.x, fv.x), fmaf(di, av.y, fv.y),
                        fmaf(di, av.z, fv.z), fmaf(di, av.w, fv.w)};
        float g1k[4] = {fmaf(-di, av.x, fv.x), fmaf(-di, av.y, fv.y),
                        fmaf(-di, av.z, fv.z), fmaf(-di, av.w, fv.w)};
        float g2k[4] = {fmaf(-di, bv.x, lv.x), fmaf(-di, bv.y, lv.y),
                        fmaf(-di, bv.z, lv.z), fmaf(-di, bv.w, lv.w)};
#pragma unroll
        for (int r = 0; r < 4; ++r) {
            int k = q * 4 + r;
            const float* w = &W2[k * HD];
#pragma unroll
            for (int j = 0; j < HD; ++j) {
                uf[j] = fmaf(f2k[r], w[j], uf[j]);
                ug[j] = fmaf(g1k[r], w[j], ug[j]);
                uh[j] = fmaf(g2k[r], w[j], uh[j]);
            }
            vf0 = fmaf(f2k[r], Wc[k * NC + 0], vf0);
            vf1 = fmaf(f2k[r], Wc[k * NC + 1], vf1);
            vg0 = fmaf(g1k[r], Wc[k * NC + 0], vg0);
            vg1 = fmaf(g1k[r], Wc[k * NC + 1], vg1);
            vh0 = fmaf(g2k[r], Wc[k * NC + 0], vh0);
            vh1 = fmaf(g2k[r], Wc[k * NC + 1], vh1);
        }
    }

    // per-layer logits
    float logits[NL];
#pragma unroll
    for (int i = 0; i < NL; ++i) {
        float wa = 0.25f * fmaxf(wbern[i * 3 + 0], 0.0f);
        float wb = 0.50f * fmaxf(wbern[i * 3 + 1], 0.0f);
        float wc = 0.25f * fmaxf(wbern[i * 3 + 2], 0.0f);
        float lg = 0.0f;
#pragma unroll
        for (int j = 0; j < HD; ++j) {
            float p = fmaf(wa, uf[j], fmaf(wb, ug[j], fmaf(wc, uh[j], b2[j])));
            lg = fmaf(fast_tanh(p), xp[j], lg);
        }
        logits[i] = lg;
    }

    // softmax over 3 + blend coefficients
    float m = fmaxf(logits[0], fmaxf(logits[1], logits[2]));
    float e0 = __expf(logits[0] - m), e1 = __expf(logits[1] - m), e2 = __expf(logits[2] - m);
    float inv = 1.0f / (e0 + e1 + e2);
    float scs[NL] = {e0 * inv, e1 * inv, e2 * inv};

    float A = 0.0f, B = 0.0f, Cc = 0.0f;
#pragma unroll
    for (int i = 0; i < NL; ++i) {
        A  += scs[i] * 0.25f * fmaxf(wbern[i * 3 + 0], 0.0f);
        B  += scs[i] * 0.50f * fmaxf(wbern[i * 3 + 1], 0.0f);
        Cc += scs[i] * 0.25f * fmaxf(wbern[i * 3 + 2], 0.0f);
    }
    out[(size_t)n * NC + 0] = bc[0] + A * vf0 + B * vg0 + Cc * vh0;
    out[(size_t)n * NC + 1] = bc[1] + A * vf1 + B * vg1 + Cc * vh1;
}

extern "C" void kernel_launch(void* const* d_in, const int* in_sizes, int n_in,
                              void* d_out, int out_size, void* d_ws, size_t ws_size,
                              hipStream_t stream) {
    const float* feature = (const float*)d_in[0];
    const float* W1 = (const float*)d_in[1];
    const float* b1 = (const float*)d_in[2];
    const float* W2 = (const float*)d_in[3];
    const float* b2 = (const float*)d_in[4];
    const float* Wc = (const float*)d_in[5];
    const float* bc = (const float*)d_in[6];
    const float* wbern = (const float*)d_in[7];
    const int* src = (const int*)d_in[8];
    const int* dst = (const int*)d_in[9];

    const int N = in_sizes[0] / FIN;   // 100000
    const int E = in_sizes[8];         // 1600000

    // workspace layout
    char* p = (char*)d_ws;
    size_t Np = ((size_t)N + 255) & ~(size_t)255;
    size_t Ep = ((size_t)E + 255) & ~(size_t)255;
    size_t N32 = (size_t)N * HD;
    int* deg_i     = (int*)p;              p += Np * 4;
    int* row_start = (int*)p;              p += Np * 4;
    int* cursor    = (int*)p;              p += Np * 4;
    int* blockSums = (int*)p;              p += 512 * 4;
    float* dinv    = (float*)p;            p += Np * 4;
    int* col       = (int*)p;              p += Ep * 4;
    float* h  = (float*)p;                 p += N32 * 4;
    float* f1 = (float*)p;                 p += N32 * 4;
    float* l1 = (float*)p;                 p += N32 * 4;
    float* t1 = (float*)p;                 p += N32 * 4;
    float* t2 = (float*)p;                 p += N32 * 4;

    hipMemsetAsync(deg_i, 0, Np * 4, stream);

    int bE = (E + 255) / 256;
    int bN = (N + 255) / 256;
    int nb = bN;                       // number of scan blocks (<=512)
    int bG = ((N * 8) + 255) / 256;

    deg_kernel<<<bE, 256, 0, stream>>>(dst, deg_i, E);
    scan_block_kernel<<<bN, 256, 0, stream>>>(deg_i, row_start, blockSums, N);
    scan_sums_kernel<<<1, 512, 0, stream>>>(blockSums, nb);
    finalize_csr_kernel<<<bN, 256, 0, stream>>>(row_start, blockSums, cursor, deg_i, dinv, N);
    fill_kernel<<<bE, 256, 0, stream>>>(src, dst, cursor, col, E);

    mlp_kernel<<<bN, 256, 0, stream>>>(feature, W1, b1, W2, b2, h, N);

    // f1 = lap2(h), l1 = lap1(h) — SpMM fused with combine
    gather1_kernel<<<bG, 256, 0, stream>>>(h, dinv, row_start, deg_i, col, f1, l1, N);
    // t1 = S(dinv*f1), t2 = S(dinv*l1) — fused edge walk
    gather2_kernel<<<bG, 256, 0, stream>>>(f1, l1, dinv, row_start, deg_i, col, t1, t2, N);

    final_kernel<<<bN, 256, 0, stream>>>(h, f1, l1, t1, t2, dinv, W2, b2, Wc, bc,
                                         wbern, (float*)d_out, N);
}

// Round 4
// 255.462 us; speedup vs baseline: 8.9796x; 1.7577x over previous
//
#include <hip/hip_runtime.h>
#include <math.h>

#define HD 32      // hidden dim
#define FIN 64     // input features
#define NL 3       // num BernConv layers
#define NC 2       // num classes

#define TILE 8192  // edges per partition tile
#define CAP  3072  // max edges per bucket (mean ~2046, 12 sigma margin)
#define BMAX 1024  // max buckets (N <= 131072 with 128 nodes/bucket)

// fast tanh via exp2-based __expf; |rel err| ~1e-7, threshold 7e-2
__device__ __forceinline__ float fast_tanh(float x) {
    float e = __expf(2.0f * x);
    return 1.0f - 2.0f * __builtin_amdgcn_rcpf(e + 1.0f);
}

// ---------------- gcursor init: gcursor[b] = b*CAP ----------------
__global__ __launch_bounds__(256) void init_kernel(int* __restrict__ gcursor, int B) {
    int b = blockIdx.x * 256 + threadIdx.x;
    if (b < B) gcursor[b] = b * CAP;
}

// ---------------- LDS-staged partition: bucket edges by dst>>7 ----------------
// Packs (src,local_dst) into u32: (src<<7)|(dst&127). src < 2^17, fits 24 bits.
// Tile-sorts 8192 edges in LDS so global writes are contiguous runs per bucket.
__global__ __launch_bounds__(256) void partition_kernel(const int* __restrict__ src,
                                                        const int* __restrict__ dst,
                                                        int* __restrict__ gcursor,
                                                        unsigned int* __restrict__ bucket_buf,
                                                        int E) {
    __shared__ unsigned int vals[TILE];
    __shared__ unsigned short bid[TILE];
    __shared__ int hist[BMAX];
    __shared__ int lcur[BMAX];
    __shared__ int goff[BMAX];
    __shared__ int sc[256];
    int t = threadIdx.x;
    int tile_base = blockIdx.x * TILE;
    int n_tile = min(TILE, E - tile_base);

    for (int i = t; i < BMAX; i += 256) hist[i] = 0;
    __syncthreads();

    unsigned int pk[TILE / 256];
    int bk[TILE / 256];
#pragma unroll
    for (int k = 0; k < TILE / 256; ++k) {
        int e = tile_base + k * 256 + t;
        if (e < E) {
            int s = src[e], d = dst[e];
            int b = d >> 7;
            pk[k] = ((unsigned)s << 7) | (unsigned)(d & 127);
            bk[k] = b;
            atomicAdd(&hist[b], 1);
        } else bk[k] = -1;
    }
    __syncthreads();

    // exclusive scan of hist[0..BMAX): 4 bins/thread + Hillis-Steele over 256
    int base4 = t * 4;
    int sum4 = hist[base4] + hist[base4 + 1] + hist[base4 + 2] + hist[base4 + 3];
    sc[t] = sum4;
    __syncthreads();
    for (int off = 1; off < 256; off <<= 1) {
        int v = (t >= off) ? sc[t - off] : 0;
        __syncthreads();
        sc[t] += v;
        __syncthreads();
    }
    int run = sc[t] - sum4;
#pragma unroll
    for (int j = 0; j < 4; ++j) {
        int tmp = hist[base4 + j];
        hist[base4 + j] = run;       // tile-local bucket start
        lcur[base4 + j] = run;
        run += tmp;
    }
    __syncthreads();

    // scatter into LDS (bucket-sorted order)
#pragma unroll
    for (int k = 0; k < TILE / 256; ++k) {
        if (bk[k] >= 0) {
            int pos = atomicAdd(&lcur[bk[k]], 1);
            vals[pos] = pk[k];
            bid[pos] = (unsigned short)bk[k];
        }
    }
    __syncthreads();

    // reserve global space per bucket
    for (int b = t; b < BMAX; b += 256) {
        int cnt = lcur[b] - hist[b];
        goff[b] = (cnt > 0) ? atomicAdd(&gcursor[b], cnt) : 0;
    }
    __syncthreads();

    // coalesced write-out: consecutive i within a bucket run -> consecutive addrs
    for (int i = t; i < n_tile; i += 256) {
        int b = bid[i];
        int addr = goff[b] + (i - hist[b]);
        if (addr < (b + 1) * CAP)                 // overflow clamp (safety)
            bucket_buf[addr] = vals[i];
    }
}

// ---------------- per-bucket CSR build (in place) ----------------
// One WG per bucket: count local deg, scan, scatter col into LDS, write back
// coalesced over the same region. Emits row_start/deg/dinv for its 128 nodes.
__global__ __launch_bounds__(256) void bucket_csr_kernel(unsigned int* bucket_buf,
                                                         const int* __restrict__ gcursor,
                                                         int* __restrict__ row_start,
                                                         int* __restrict__ degA,
                                                         float* __restrict__ dinv,
                                                         int N) {
    __shared__ int ldeg[128], lexc[128], lcur2[128];
    __shared__ int colLDS[CAP];
    int b = blockIdx.x;
    int t = threadIdx.x;
    int base = b * CAP;
    int cnt = min(gcursor[b] - base, CAP);

    if (t < 128) ldeg[t] = 0;
    __syncthreads();
    for (int i = t; i < cnt; i += 256)
        atomicAdd(&ldeg[bucket_buf[base + i] & 127], 1);
    __syncthreads();

    if (t < 128) lexc[t] = ldeg[t];
    __syncthreads();
    for (int off = 1; off < 128; off <<= 1) {
        int v = (t >= off && t < 128) ? lexc[t - off] : 0;
        __syncthreads();
        if (t < 128) lexc[t] += v;
        __syncthreads();
    }
    if (t < 128) {
        int ex = lexc[t] - ldeg[t];
        lcur2[t] = ex;
        int node = (b << 7) + t;
        if (node < N) {
            row_start[node] = base + ex;
            degA[node] = ldeg[t];
            dinv[node] = rsqrtf(fmaxf((float)ldeg[t], 1.0f));
        }
    }
    __syncthreads();

    for (int i = t; i < cnt; i += 256) {
        unsigned int v = bucket_buf[base + i];
        int pos = atomicAdd(&lcur2[(int)(v & 127)], 1);
        colLDS[pos] = (int)(v >> 7);
    }
    __syncthreads();
    for (int i = t; i < cnt; i += 256)
        bucket_buf[base + i] = (unsigned int)colLDS[i];   // now = col[]
}

// ---------------- MLP in: h = relu(feat@W1+b1)@W2+b2 ----------------
__global__ __launch_bounds__(256) void mlp_kernel(const float* __restrict__ feat,
                                                  const float* __restrict__ W1,
                                                  const float* __restrict__ b1,
                                                  const float* __restrict__ W2,
                                                  const float* __restrict__ b2,
                                                  float* __restrict__ hout, int N) {
    int n = blockIdx.x * 256 + threadIdx.x;
    if (n >= N) return;

    float h1[HD];
#pragma unroll
    for (int j = 0; j < HD; ++j) h1[j] = b1[j];
    const float4* fp = (const float4*)feat;
#pragma unroll
    for (int k4 = 0; k4 < FIN / 4; ++k4) {
        float4 v = fp[(size_t)n * (FIN / 4) + k4];
        const float* w = &W1[k4 * 4 * HD];
#pragma unroll
        for (int j = 0; j < HD; ++j)
            h1[j] = fmaf(v.w, w[3 * HD + j],
                    fmaf(v.z, w[2 * HD + j],
                    fmaf(v.y, w[1 * HD + j],
                    fmaf(v.x, w[0 * HD + j], h1[j]))));
    }
    float h2[HD];
#pragma unroll
    for (int j = 0; j < HD; ++j) h2[j] = b2[j];
#pragma unroll
    for (int k = 0; k < HD; ++k) {
        float a = fmaxf(h1[k], 0.0f);
#pragma unroll
        for (int j = 0; j < HD; ++j) h2[j] = fmaf(a, W2[k * HD + j], h2[j]);
    }
    float4* op = (float4*)hout;
#pragma unroll
    for (int q = 0; q < HD / 4; ++q) {
        float4 v = {h2[4 * q], h2[4 * q + 1], h2[4 * q + 2], h2[4 * q + 3]};
        op[(size_t)n * (HD / 4) + q] = v;
    }
}

// ---------------- gather #1: s0 = S(d*h); f1 = h + d*s0 ----------------
__global__ __launch_bounds__(256) void gather1_kernel(const float* __restrict__ h,
                                                      const float* __restrict__ dinv,
                                                      const int* __restrict__ row_start,
                                                      const int* __restrict__ deg,
                                                      const int* __restrict__ col,
                                                      float* __restrict__ f1,
                                                      float* __restrict__ s0, int N) {
    int t = blockIdx.x * 256 + threadIdx.x;
    int n = t >> 3;
    if (n >= N) return;
    int q = t & 7;
    int s = row_start[n];
    int e_end = s + deg[n];
    float4 acc = {0.f, 0.f, 0.f, 0.f};
    const float4* x4 = (const float4*)h;
    for (int e = s; e < e_end; ++e) {
        int c = col[e];
        float sc = dinv[c];
        float4 v = x4[(size_t)c * 8 + q];
        acc.x = fmaf(v.x, sc, acc.x);
        acc.y = fmaf(v.y, sc, acc.y);
        acc.z = fmaf(v.z, sc, acc.z);
        acc.w = fmaf(v.w, sc, acc.w);
    }
    float di = dinv[n];
    float4 hv = x4[(size_t)n * 8 + q];
    float4 fo = {fmaf(di, acc.x, hv.x), fmaf(di, acc.y, hv.y),
                 fmaf(di, acc.z, hv.z), fmaf(di, acc.w, hv.w)};
    ((float4*)f1)[(size_t)n * 8 + q] = fo;
    ((float4*)s0)[(size_t)n * 8 + q] = acc;
}

// ---------------- gather #2: t1 = S(d*f1) (t2 = 2*s0 - t1 by linearity) ----
__global__ __launch_bounds__(256) void gather2_kernel(const float* __restrict__ f1,
                                                      const float* __restrict__ dinv,
                                                      const int* __restrict__ row_start,
                                                      const int* __restrict__ deg,
                                                      const int* __restrict__ col,
                                                      float* __restrict__ t1, int N) {
    int t = blockIdx.x * 256 + threadIdx.x;
    int n = t >> 3;
    if (n >= N) return;
    int q = t & 7;
    int s = row_start[n];
    int e_end = s + deg[n];
    float4 acc = {0.f, 0.f, 0.f, 0.f};
    const float4* x4 = (const float4*)f1;
    for (int e = s; e < e_end; ++e) {
        int c = col[e];
        float sc = dinv[c];
        float4 v = x4[(size_t)c * 8 + q];
        acc.x = fmaf(v.x, sc, acc.x);
        acc.y = fmaf(v.y, sc, acc.y);
        acc.z = fmaf(v.z, sc, acc.z);
        acc.w = fmaf(v.w, sc, acc.w);
    }
    ((float4*)t1)[(size_t)n * 8 + q] = acc;
}

// ---------------- fused epilogue ----------------
// Bases from (h, s0, t1): f2 = h + d*s0 + d*t1; g1 = h + d*s0 - d*t1;
// g2 = h - 3d*s0 + d*t1. Stream quads; accumulate W2/Wc projections.
__global__ __launch_bounds__(256) void final_kernel(const float* __restrict__ h,
                                                    const float* __restrict__ s0,
                                                    const float* __restrict__ t1,
                                                    const float* __restrict__ dinv,
                                                    const float* __restrict__ W2,
                                                    const float* __restrict__ b2,
                                                    const float* __restrict__ Wc,
                                                    const float* __restrict__ bc,
                                                    const float* __restrict__ wbern,
                                                    float* __restrict__ out, int N) {
    int n = blockIdx.x * 256 + threadIdx.x;
    if (n >= N) return;
    float di = dinv[n];

    // xp = tanh(h@W2 + b2)  — also captures h quads for base recompute
    float xp[HD];
#pragma unroll
    for (int j = 0; j < HD; ++j) xp[j] = b2[j];
    const float4* h4 = (const float4*)h;
    const float4* s04 = (const float4*)s0;
    const float4* t14 = (const float4*)t1;
#pragma unroll
    for (int q = 0; q < 8; ++q) {
        float4 v = h4[(size_t)n * 8 + q];
        const float* w = &W2[q * 4 * HD];
#pragma unroll
        for (int j = 0; j < HD; ++j)
            xp[j] = fmaf(v.w, w[3 * HD + j],
                    fmaf(v.z, w[2 * HD + j],
                    fmaf(v.y, w[1 * HD + j],
                    fmaf(v.x, w[0 * HD + j], xp[j]))));
    }
#pragma unroll
    for (int j = 0; j < HD; ++j) xp[j] = fast_tanh(xp[j]);

    float uf[HD], ug[HD], uh[HD];
#pragma unroll
    for (int j = 0; j < HD; ++j) { uf[j] = 0.f; ug[j] = 0.f; uh[j] = 0.f; }
    float vf0 = 0.f, vf1 = 0.f, vg0 = 0.f, vg1 = 0.f, vh0 = 0.f, vh1 = 0.f;
#pragma unroll
    for (int q = 0; q < 8; ++q) {
        float4 hv = h4[(size_t)n * 8 + q];
        float4 av = s04[(size_t)n * 8 + q];
        float4 bv = t14[(size_t)n * 8 + q];
        float da[4] = {di * av.x, di * av.y, di * av.z, di * av.w};
        float db[4] = {di * bv.x, di * bv.y, di * bv.z, di * bv.w};
        float hq[4] = {hv.x, hv.y, hv.z, hv.w};
        float f2k[4], g1k[4], g2k[4];
#pragma unroll
        for (int r = 0; r < 4; ++r) {
            f2k[r] = hq[r] + da[r] + db[r];
            g1k[r] = hq[r] + da[r] - db[r];
            g2k[r] = hq[r] - 3.0f * da[r] + db[r];
        }
#pragma unroll
        for (int r = 0; r < 4; ++r) {
            int k = q * 4 + r;
            const float* w = &W2[k * HD];
#pragma unroll
            for (int j = 0; j < HD; ++j) {
                uf[j] = fmaf(f2k[r], w[j], uf[j]);
                ug[j] = fmaf(g1k[r], w[j], ug[j]);
                uh[j] = fmaf(g2k[r], w[j], uh[j]);
            }
            vf0 = fmaf(f2k[r], Wc[k * NC + 0], vf0);
            vf1 = fmaf(f2k[r], Wc[k * NC + 1], vf1);
            vg0 = fmaf(g1k[r], Wc[k * NC + 0], vg0);
            vg1 = fmaf(g1k[r], Wc[k * NC + 1], vg1);
            vh0 = fmaf(g2k[r], Wc[k * NC + 0], vh0);
            vh1 = fmaf(g2k[r], Wc[k * NC + 1], vh1);
        }
    }

    float logits[NL];
#pragma unroll
    for (int i = 0; i < NL; ++i) {
        float wa = 0.25f * fmaxf(wbern[i * 3 + 0], 0.0f);
        float wb = 0.50f * fmaxf(wbern[i * 3 + 1], 0.0f);
        float wc = 0.25f * fmaxf(wbern[i * 3 + 2], 0.0f);
        float lg = 0.0f;
#pragma unroll
        for (int j = 0; j < HD; ++j) {
            float p = fmaf(wa, uf[j], fmaf(wb, ug[j], fmaf(wc, uh[j], b2[j])));
            lg = fmaf(fast_tanh(p), xp[j], lg);
        }
        logits[i] = lg;
    }

    float m = fmaxf(logits[0], fmaxf(logits[1], logits[2]));
    float e0 = __expf(logits[0] - m), e1 = __expf(logits[1] - m), e2 = __expf(logits[2] - m);
    float inv = 1.0f / (e0 + e1 + e2);
    float scs[NL] = {e0 * inv, e1 * inv, e2 * inv};

    float A = 0.0f, B = 0.0f, Cc = 0.0f;
#pragma unroll
    for (int i = 0; i < NL; ++i) {
        A  += scs[i] * 0.25f * fmaxf(wbern[i * 3 + 0], 0.0f);
        B  += scs[i] * 0.50f * fmaxf(wbern[i * 3 + 1], 0.0f);
        Cc += scs[i] * 0.25f * fmaxf(wbern[i * 3 + 2], 0.0f);
    }
    out[(size_t)n * NC + 0] = bc[0] + A * vf0 + B * vg0 + Cc * vh0;
    out[(size_t)n * NC + 1] = bc[1] + A * vf1 + B * vg1 + Cc * vh1;
}

extern "C" void kernel_launch(void* const* d_in, const int* in_sizes, int n_in,
                              void* d_out, int out_size, void* d_ws, size_t ws_size,
                              hipStream_t stream) {
    const float* feature = (const float*)d_in[0];
    const float* W1 = (const float*)d_in[1];
    const float* b1 = (const float*)d_in[2];
    const float* W2 = (const float*)d_in[3];
    const float* b2 = (const float*)d_in[4];
    const float* Wc = (const float*)d_in[5];
    const float* bc = (const float*)d_in[6];
    const float* wbern = (const float*)d_in[7];
    const int* src = (const int*)d_in[8];
    const int* dst = (const int*)d_in[9];

    const int N = in_sizes[0] / FIN;   // 100000
    const int E = in_sizes[8];         // 1600000
    const int B = (N + 127) >> 7;      // 782 buckets

    // workspace layout
    char* p = (char*)d_ws;
    size_t Np = ((size_t)N + 255) & ~(size_t)255;
    size_t N32 = (size_t)N * HD;
    int* gcursor   = (int*)p;              p += ((size_t)BMAX) * 4;
    int* row_start = (int*)p;              p += Np * 4;
    int* degA      = (int*)p;              p += Np * 4;
    float* dinv    = (float*)p;            p += Np * 4;
    unsigned int* bucket_buf = (unsigned int*)p;  p += (size_t)B * CAP * 4;  // becomes col[]
    float* h  = (float*)p;                 p += N32 * 4;
    float* f1 = (float*)p;                 p += N32 * 4;
    float* s0 = (float*)p;                 p += N32 * 4;
    float* t1 = (float*)p;                 p += N32 * 4;

    int bN = (N + 255) / 256;
    int bG = ((N * 8) + 255) / 256;
    int nTiles = (E + TILE - 1) / TILE;

    init_kernel<<<(B + 255) / 256, 256, 0, stream>>>(gcursor, B);
    partition_kernel<<<nTiles, 256, 0, stream>>>(src, dst, gcursor, bucket_buf, E);
    bucket_csr_kernel<<<B, 256, 0, stream>>>(bucket_buf, gcursor, row_start, degA, dinv, N);

    mlp_kernel<<<bN, 256, 0, stream>>>(feature, W1, b1, W2, b2, h, N);

    const int* col = (const int*)bucket_buf;
    gather1_kernel<<<bG, 256, 0, stream>>>(h, dinv, row_start, degA, col, f1, s0, N);
    gather2_kernel<<<bG, 256, 0, stream>>>(f1, dinv, row_start, degA, col, t1, N);

    final_kernel<<<bN, 256, 0, stream>>>(h, s0, t1, dinv, W2, b2, Wc, bc,
                                         wbern, (float*)d_out, N);
}

// Round 5
// 238.055 us; speedup vs baseline: 9.6362x; 1.0731x over previous
//
#include <hip/hip_runtime.h>
#include <math.h>

#define HD 32      // hidden dim
#define FIN 64     // input features
#define NL 3       // num BernConv layers
#define NC 2       // num classes

#define TILE 8192  // edges per partition tile
#define CAP  3072  // max edges per bucket (mean ~2046, 12 sigma margin)
#define BMAX 1024  // max buckets (N <= 131072 with 128 nodes/bucket)

// fast tanh; |rel err| ~1e-7, threshold 7e-2
__device__ __forceinline__ float fast_tanh(float x) {
    float e = __expf(2.0f * x);
    return 1.0f - 2.0f * __builtin_amdgcn_rcpf(e + 1.0f);
}

// fp32 -> bf16 bits with round-to-nearest-even (values are finite here)
__device__ __forceinline__ unsigned int f2bf(float f) {
    unsigned int u = __float_as_uint(f);
    return (u + 0x7fffu + ((u >> 16) & 1u)) >> 16;
}
__device__ __forceinline__ unsigned int pack2(float lo, float hi) {
    return f2bf(lo) | (f2bf(hi) << 16);
}
// bf16 pair -> fp32 (exact, just bit shifts)
__device__ __forceinline__ float bflo(unsigned int u) { return __uint_as_float(u << 16); }
__device__ __forceinline__ float bfhi(unsigned int u) { return __uint_as_float(u & 0xffff0000u); }

// ---------------- gcursor init ----------------
__global__ __launch_bounds__(256) void init_kernel(int* __restrict__ gcursor, int B) {
    int b = blockIdx.x * 256 + threadIdx.x;
    if (b < B) gcursor[b] = b * CAP;
}

// ---------------- LDS-staged partition: bucket edges by dst>>7 ----------------
__global__ __launch_bounds__(256) void partition_kernel(const int* __restrict__ src,
                                                        const int* __restrict__ dst,
                                                        int* __restrict__ gcursor,
                                                        unsigned int* __restrict__ bucket_buf,
                                                        int E) {
    __shared__ unsigned int vals[TILE];
    __shared__ unsigned short bid[TILE];
    __shared__ int hist[BMAX];
    __shared__ int lcur[BMAX];
    __shared__ int goff[BMAX];
    __shared__ int sc[256];
    int t = threadIdx.x;
    int tile_base = blockIdx.x * TILE;
    int n_tile = min(TILE, E - tile_base);

    for (int i = t; i < BMAX; i += 256) hist[i] = 0;
    __syncthreads();

    unsigned int pk[TILE / 256];
    int bk[TILE / 256];
#pragma unroll
    for (int k = 0; k < TILE / 256; ++k) {
        int e = tile_base + k * 256 + t;
        if (e < E) {
            int s = src[e], d = dst[e];
            int b = d >> 7;
            pk[k] = ((unsigned)s << 7) | (unsigned)(d & 127);
            bk[k] = b;
            atomicAdd(&hist[b], 1);
        } else bk[k] = -1;
    }
    __syncthreads();

    int base4 = t * 4;
    int sum4 = hist[base4] + hist[base4 + 1] + hist[base4 + 2] + hist[base4 + 3];
    sc[t] = sum4;
    __syncthreads();
    for (int off = 1; off < 256; off <<= 1) {
        int v = (t >= off) ? sc[t - off] : 0;
        __syncthreads();
        sc[t] += v;
        __syncthreads();
    }
    int run = sc[t] - sum4;
#pragma unroll
    for (int j = 0; j < 4; ++j) {
        int tmp = hist[base4 + j];
        hist[base4 + j] = run;
        lcur[base4 + j] = run;
        run += tmp;
    }
    __syncthreads();

#pragma unroll
    for (int k = 0; k < TILE / 256; ++k) {
        if (bk[k] >= 0) {
            int pos = atomicAdd(&lcur[bk[k]], 1);
            vals[pos] = pk[k];
            bid[pos] = (unsigned short)bk[k];
        }
    }
    __syncthreads();

    for (int b = t; b < BMAX; b += 256) {
        int cnt = lcur[b] - hist[b];
        goff[b] = (cnt > 0) ? atomicAdd(&gcursor[b], cnt) : 0;
    }
    __syncthreads();

    for (int i = t; i < n_tile; i += 256) {
        int b = bid[i];
        int addr = goff[b] + (i - hist[b]);
        if (addr < (b + 1) * CAP)
            bucket_buf[addr] = vals[i];
    }
}

// ---------------- per-bucket CSR build (in place) ----------------
__global__ __launch_bounds__(256) void bucket_csr_kernel(unsigned int* bucket_buf,
                                                         const int* __restrict__ gcursor,
                                                         int* __restrict__ row_start,
                                                         int* __restrict__ degA,
                                                         float* __restrict__ dinv,
                                                         int N) {
    __shared__ int ldeg[128], lexc[128], lcur2[128];
    __shared__ int colLDS[CAP];
    int b = blockIdx.x;
    int t = threadIdx.x;
    int base = b * CAP;
    int cnt = min(gcursor[b] - base, CAP);

    if (t < 128) ldeg[t] = 0;
    __syncthreads();
    for (int i = t; i < cnt; i += 256)
        atomicAdd(&ldeg[bucket_buf[base + i] & 127], 1);
    __syncthreads();

    if (t < 128) lexc[t] = ldeg[t];
    __syncthreads();
    for (int off = 1; off < 128; off <<= 1) {
        int v = (t >= off && t < 128) ? lexc[t - off] : 0;
        __syncthreads();
        if (t < 128) lexc[t] += v;
        __syncthreads();
    }
    if (t < 128) {
        int ex = lexc[t] - ldeg[t];
        lcur2[t] = ex;
        int node = (b << 7) + t;
        if (node < N) {
            row_start[node] = base + ex;
            degA[node] = ldeg[t];
            dinv[node] = rsqrtf(fmaxf((float)ldeg[t], 1.0f));
        }
    }
    __syncthreads();

    for (int i = t; i < cnt; i += 256) {
        unsigned int v = bucket_buf[base + i];
        int pos = atomicAdd(&lcur2[(int)(v & 127)], 1);
        colLDS[pos] = (int)(v >> 7);
    }
    __syncthreads();
    for (int i = t; i < cnt; i += 256)
        bucket_buf[base + i] = (unsigned int)colLDS[i];   // now = col[]
}

// ---------------- MLP in: h = relu(feat@W1+b1)@W2+b2 ----------------
// Also emits hs_b = bf16(dinv[n] * h[n]) — the gather operand (one 64B line/row).
__global__ __launch_bounds__(256) void mlp_kernel(const float* __restrict__ feat,
                                                  const float* __restrict__ W1,
                                                  const float* __restrict__ b1,
                                                  const float* __restrict__ W2,
                                                  const float* __restrict__ b2,
                                                  const float* __restrict__ dinv,
                                                  float* __restrict__ hout,
                                                  uint4* __restrict__ hs_b, int N) {
    int n = blockIdx.x * 256 + threadIdx.x;
    if (n >= N) return;

    float h1[HD];
#pragma unroll
    for (int j = 0; j < HD; ++j) h1[j] = b1[j];
    const float4* fp = (const float4*)feat;
#pragma unroll
    for (int k4 = 0; k4 < FIN / 4; ++k4) {
        float4 v = fp[(size_t)n * (FIN / 4) + k4];
        const float* w = &W1[k4 * 4 * HD];
#pragma unroll
        for (int j = 0; j < HD; ++j)
            h1[j] = fmaf(v.w, w[3 * HD + j],
                    fmaf(v.z, w[2 * HD + j],
                    fmaf(v.y, w[1 * HD + j],
                    fmaf(v.x, w[0 * HD + j], h1[j]))));
    }
    float h2[HD];
#pragma unroll
    for (int j = 0; j < HD; ++j) h2[j] = b2[j];
#pragma unroll
    for (int k = 0; k < HD; ++k) {
        float a = fmaxf(h1[k], 0.0f);
#pragma unroll
        for (int j = 0; j < HD; ++j) h2[j] = fmaf(a, W2[k * HD + j], h2[j]);
    }
    float4* op = (float4*)hout;
#pragma unroll
    for (int q = 0; q < HD / 4; ++q) {
        float4 v = {h2[4 * q], h2[4 * q + 1], h2[4 * q + 2], h2[4 * q + 3]};
        op[(size_t)n * (HD / 4) + q] = v;
    }
    float di = dinv[n];
#pragma unroll
    for (int q = 0; q < 4; ++q) {
        uint4 u;
        u.x = pack2(di * h2[8 * q + 0], di * h2[8 * q + 1]);
        u.y = pack2(di * h2[8 * q + 2], di * h2[8 * q + 3]);
        u.z = pack2(di * h2[8 * q + 4], di * h2[8 * q + 5]);
        u.w = pack2(di * h2[8 * q + 6], di * h2[8 * q + 7]);
        hs_b[(size_t)n * 4 + q] = u;
    }
}

// ---------------- gather #1: acc = sum hs[col]; s0 = acc (fp32);
//                  f1s_b = bf16(dinv[n]*(h[n] + dinv[n]*acc)) ----------------
// 4 lanes/node, lane q handles features [8q, 8q+8)
__global__ __launch_bounds__(256) void gather1_kernel(const float* __restrict__ h,
                                                      const uint4* __restrict__ hs_b,
                                                      const float* __restrict__ dinv,
                                                      const int* __restrict__ row_start,
                                                      const int* __restrict__ deg,
                                                      const int* __restrict__ col,
                                                      float* __restrict__ s0,
                                                      uint4* __restrict__ f1s_b, int N) {
    int t = blockIdx.x * 256 + threadIdx.x;
    int n = t >> 2;
    if (n >= N) return;
    int q = t & 3;
    int s = row_start[n];
    int e_end = s + deg[n];
    float acc[8] = {0.f, 0.f, 0.f, 0.f, 0.f, 0.f, 0.f, 0.f};
    for (int e = s; e < e_end; ++e) {
        int c = col[e];
        uint4 v = hs_b[(size_t)c * 4 + q];
        acc[0] += bflo(v.x); acc[1] += bfhi(v.x);
        acc[2] += bflo(v.y); acc[3] += bfhi(v.y);
        acc[4] += bflo(v.z); acc[5] += bfhi(v.z);
        acc[6] += bflo(v.w); acc[7] += bfhi(v.w);
    }
    float di = dinv[n];
    const float4* h4 = (const float4*)h;
    float4 ha = h4[(size_t)n * 8 + 2 * q];
    float4 hb = h4[(size_t)n * 8 + 2 * q + 1];
    float f[8] = {fmaf(di, acc[0], ha.x), fmaf(di, acc[1], ha.y),
                  fmaf(di, acc[2], ha.z), fmaf(di, acc[3], ha.w),
                  fmaf(di, acc[4], hb.x), fmaf(di, acc[5], hb.y),
                  fmaf(di, acc[6], hb.z), fmaf(di, acc[7], hb.w)};
    float4 sa = {acc[0], acc[1], acc[2], acc[3]};
    float4 sb = {acc[4], acc[5], acc[6], acc[7]};
    ((float4*)s0)[(size_t)n * 8 + 2 * q] = sa;
    ((float4*)s0)[(size_t)n * 8 + 2 * q + 1] = sb;
    uint4 u;
    u.x = pack2(di * f[0], di * f[1]);
    u.y = pack2(di * f[2], di * f[3]);
    u.z = pack2(di * f[4], di * f[5]);
    u.w = pack2(di * f[6], di * f[7]);
    f1s_b[(size_t)n * 4 + q] = u;
}

// ---------------- gather #2: t1 = sum f1s[col] (fp32 out) ----------------
__global__ __launch_bounds__(256) void gather2_kernel(const uint4* __restrict__ f1s_b,
                                                      const int* __restrict__ row_start,
                                                      const int* __restrict__ deg,
                                                      const int* __restrict__ col,
                                                      float* __restrict__ t1, int N) {
    int t = blockIdx.x * 256 + threadIdx.x;
    int n = t >> 2;
    if (n >= N) return;
    int q = t & 3;
    int s = row_start[n];
    int e_end = s + deg[n];
    float acc[8] = {0.f, 0.f, 0.f, 0.f, 0.f, 0.f, 0.f, 0.f};
    for (int e = s; e < e_end; ++e) {
        int c = col[e];
        uint4 v = f1s_b[(size_t)c * 4 + q];
        acc[0] += bflo(v.x); acc[1] += bfhi(v.x);
        acc[2] += bflo(v.y); acc[3] += bfhi(v.y);
        acc[4] += bflo(v.z); acc[5] += bfhi(v.z);
        acc[6] += bflo(v.w); acc[7] += bfhi(v.w);
    }
    float4 sa = {acc[0], acc[1], acc[2], acc[3]};
    float4 sb = {acc[4], acc[5], acc[6], acc[7]};
    ((float4*)t1)[(size_t)n * 8 + 2 * q] = sa;
    ((float4*)t1)[(size_t)n * 8 + 2 * q + 1] = sb;
}

// ---------------- fused epilogue ----------------
// Bases: f2 = h + d*s0 + d*t1; g1 = h + d*s0 - d*t1; g2 = h - 3d*s0 + d*t1
__global__ __launch_bounds__(256) void final_kernel(const float* __restrict__ h,
                                                    const float* __restrict__ s0,
                                                    const float* __restrict__ t1,
                                                    const float* __restrict__ dinv,
                                                    const float* __restrict__ W2,
                                                    const float* __restrict__ b2,
                                                    const float* __restrict__ Wc,
                                                    const float* __restrict__ bc,
                                                    const float* __restrict__ wbern,
                                                    float* __restrict__ out, int N) {
    int n = blockIdx.x * 256 + threadIdx.x;
    if (n >= N) return;
    float di = dinv[n];

    float xp[HD];
#pragma unroll
    for (int j = 0; j < HD; ++j) xp[j] = b2[j];
    const float4* h4 = (const float4*)h;
    const float4* s04 = (const float4*)s0;
    const float4* t14 = (const float4*)t1;
#pragma unroll
    for (int q = 0; q < 8; ++q) {
        float4 v = h4[(size_t)n * 8 + q];
        const float* w = &W2[q * 4 * HD];
#pragma unroll
        for (int j = 0; j < HD; ++j)
            xp[j] = fmaf(v.w, w[3 * HD + j],
                    fmaf(v.z, w[2 * HD + j],
                    fmaf(v.y, w[1 * HD + j],
                    fmaf(v.x, w[0 * HD + j], xp[j]))));
    }
#pragma unroll
    for (int j = 0; j < HD; ++j) xp[j] = fast_tanh(xp[j]);

    float uf[HD], ug[HD], uh[HD];
#pragma unroll
    for (int j = 0; j < HD; ++j) { uf[j] = 0.f; ug[j] = 0.f; uh[j] = 0.f; }
    float vf0 = 0.f, vf1 = 0.f, vg0 = 0.f, vg1 = 0.f, vh0 = 0.f, vh1 = 0.f;
#pragma unroll
    for (int q = 0; q < 8; ++q) {
        float4 hv = h4[(size_t)n * 8 + q];
        float4 av = s04[(size_t)n * 8 + q];
        float4 bv = t14[(size_t)n * 8 + q];
        float da[4] = {di * av.x, di * av.y, di * av.z, di * av.w};
        float db[4] = {di * bv.x, di * bv.y, di * bv.z, di * bv.w};
        float hq[4] = {hv.x, hv.y, hv.z, hv.w};
        float f2k[4], g1k[4], g2k[4];
#pragma unroll
        for (int r = 0; r < 4; ++r) {
            f2k[r] = hq[r] + da[r] + db[r];
            g1k[r] = hq[r] + da[r] - db[r];
            g2k[r] = hq[r] - 3.0f * da[r] + db[r];
        }
#pragma unroll
        for (int r = 0; r < 4; ++r) {
            int k = q * 4 + r;
            const float* w = &W2[k * HD];
#pragma unroll
            for (int j = 0; j < HD; ++j) {
                uf[j] = fmaf(f2k[r], w[j], uf[j]);
                ug[j] = fmaf(g1k[r], w[j], ug[j]);
                uh[j] = fmaf(g2k[r], w[j], uh[j]);
            }
            vf0 = fmaf(f2k[r], Wc[k * NC + 0], vf0);
            vf1 = fmaf(f2k[r], Wc[k * NC + 1], vf1);
            vg0 = fmaf(g1k[r], Wc[k * NC + 0], vg0);
            vg1 = fmaf(g1k[r], Wc[k * NC + 1], vg1);
            vh0 = fmaf(g2k[r], Wc[k * NC + 0], vh0);
            vh1 = fmaf(g2k[r], Wc[k * NC + 1], vh1);
        }
    }

    float logits[NL];
#pragma unroll
    for (int i = 0; i < NL; ++i) {
        float wa = 0.25f * fmaxf(wbern[i * 3 + 0], 0.0f);
        float wb = 0.50f * fmaxf(wbern[i * 3 + 1], 0.0f);
        float wc = 0.25f * fmaxf(wbern[i * 3 + 2], 0.0f);
        float lg = 0.0f;
#pragma unroll
        for (int j = 0; j < HD; ++j) {
            float p = fmaf(wa, uf[j], fmaf(wb, ug[j], fmaf(wc, uh[j], b2[j])));
            lg = fmaf(fast_tanh(p), xp[j], lg);
        }
        logits[i] = lg;
    }

    float m = fmaxf(logits[0], fmaxf(logits[1], logits[2]));
    float e0 = __expf(logits[0] - m), e1 = __expf(logits[1] - m), e2 = __expf(logits[2] - m);
    float inv = 1.0f / (e0 + e1 + e2);
    float scs[NL] = {e0 * inv, e1 * inv, e2 * inv};

    float A = 0.0f, B = 0.0f, Cc = 0.0f;
#pragma unroll
    for (int i = 0; i < NL; ++i) {
        A  += scs[i] * 0.25f * fmaxf(wbern[i * 3 + 0], 0.0f);
        B  += scs[i] * 0.50f * fmaxf(wbern[i * 3 + 1], 0.0f);
        Cc += scs[i] * 0.25f * fmaxf(wbern[i * 3 + 2], 0.0f);
    }
    out[(size_t)n * NC + 0] = bc[0] + A * vf0 + B * vg0 + Cc * vh0;
    out[(size_t)n * NC + 1] = bc[1] + A * vf1 + B * vg1 + Cc * vh1;
}

extern "C" void kernel_launch(void* const* d_in, const int* in_sizes, int n_in,
                              void* d_out, int out_size, void* d_ws, size_t ws_size,
                              hipStream_t stream) {
    const float* feature = (const float*)d_in[0];
    const float* W1 = (const float*)d_in[1];
    const float* b1 = (const float*)d_in[2];
    const float* W2 = (const float*)d_in[3];
    const float* b2 = (const float*)d_in[4];
    const float* Wc = (const float*)d_in[5];
    const float* bc = (const float*)d_in[6];
    const float* wbern = (const float*)d_in[7];
    const int* src = (const int*)d_in[8];
    const int* dst = (const int*)d_in[9];

    const int N = in_sizes[0] / FIN;   // 100000
    const int E = in_sizes[8];         // 1600000
    const int B = (N + 127) >> 7;      // 782 buckets

    // workspace layout
    char* p = (char*)d_ws;
    size_t Np = ((size_t)N + 255) & ~(size_t)255;
    size_t N32 = (size_t)N * HD;
    int* gcursor   = (int*)p;              p += ((size_t)BMAX) * 4;
    int* row_start = (int*)p;              p += Np * 4;
    int* degA      = (int*)p;              p += Np * 4;
    float* dinv    = (float*)p;            p += Np * 4;
    unsigned int* bucket_buf = (unsigned int*)p;  p += (size_t)B * CAP * 4;  // becomes col[]
    float* h    = (float*)p;               p += N32 * 4;
    float* s0   = (float*)p;               p += N32 * 4;
    float* t1   = (float*)p;               p += N32 * 4;
    uint4* hs_b = (uint4*)p;               p += N32 * 2;   // bf16, 64B/row
    uint4* f1s_b= (uint4*)p;               p += N32 * 2;

    int bN = (N + 255) / 256;
    int bG = ((N * 4) + 255) / 256;
    int nTiles = (E + TILE - 1) / TILE;

    init_kernel<<<(B + 255) / 256, 256, 0, stream>>>(gcursor, B);
    partition_kernel<<<nTiles, 256, 0, stream>>>(src, dst, gcursor, bucket_buf, E);
    bucket_csr_kernel<<<B, 256, 0, stream>>>(bucket_buf, gcursor, row_start, degA, dinv, N);

    mlp_kernel<<<bN, 256, 0, stream>>>(feature, W1, b1, W2, b2, dinv, h, hs_b, N);

    const int* col = (const int*)bucket_buf;
    gather1_kernel<<<bG, 256, 0, stream>>>(h, hs_b, dinv, row_start, degA, col, s0, f1s_b, N);
    gather2_kernel<<<bG, 256, 0, stream>>>(f1s_b, row_start, degA, col, t1, N);

    final_kernel<<<bN, 256, 0, stream>>>(h, s0, t1, dinv, W2, b2, Wc, bc,
                                         wbern, (float*)d_out, N);
}